// Round 7
// baseline (158.532 us; speedup 1.0000x reference)
//
#include <hip/hip_runtime.h>

#define MAX_L 2048   // max phonemes per batch for LDS cumsum
#define MAX_EPC 8    // max cum elements per thread (L <= 256*8)
#define FPB 128      // frames per block
#define ROWS 16      // staged feature rows per chunk (D=256 -> 16 KiB)

// Fused length-regulator with LDS row staging.
// One 256-thread block per 128 output frames:
//   1) block computes its batch's duration cumsum in LDS (shuffle scan)
//   2) 128 threads binary-search in LDS -> sidx[128] (phoneme idx; valid
//      frames are a prefix, and sidx is monotone over them)
//   3) chunked copy: stage the chunk's (contiguous) phoneme rows into LDS
//      with coalesced independent global loads, then stream stores whose
//      data comes from ds_read. LDS reads wait on lgkmcnt — they never
//      drain the vmcnt store queue — so stores issue back-to-back like a
//      memset (the 6.5 TB/s fill proves that shape hits HBM peak).
__global__ __launch_bounds__(256) void lr_fused_kernel(
        const float* __restrict__ feat,
        const int* __restrict__ dur,
        const int* __restrict__ tlen,
        float* __restrict__ out,
        int BL, int BT, int D) {
    const int T = *tlen;
    const int B = BT / T;
    const int L = BL / B;
    const int vecs = D >> 2;

    __shared__ int sc[MAX_L];
    __shared__ int swsum[4];
    __shared__ int sidx[FPB];
    __shared__ float4 srows[ROWS * 64];
    __shared__ int sf2;

    const long frame_base0 = (long)blockIdx.x * FPB;
    if (frame_base0 >= BT) return;

    const int tid  = threadIdx.x;
    const int lane = tid & 63;
    const int wv   = tid >> 6;

    long fb_ = frame_base0;
    long rem_l = (long)BT - frame_base0;
    int remaining = (int)(rem_l < FPB ? rem_l : (long)FPB);

    // Segment loop (block-uniform): one iteration when T % FPB == 0.
    while (remaining > 0) {
        const int b   = (int)(fb_ / T);
        const int tt0 = (int)(fb_ - (long)b * T);
        const int seg = remaining < (T - tt0) ? remaining : (T - tt0);

        // ---- cumsum of batch b's duration row into sc ----
        __syncthreads();  // protect sc/sidx/srows reuse across segments
        const int epc  = (L + blockDim.x - 1) / blockDim.x;
        const int base = tid * epc;
        const int* __restrict__ drow = dur + (size_t)b * L;
        int local[MAX_EPC];
        int run = 0;
#pragma unroll
        for (int e = 0; e < MAX_EPC; ++e) {
            int v = 0;
            if (e < epc && base + e < L) v = drow[base + e];
            run += v;
            local[e] = run;
        }
        int wsum = run;
#pragma unroll
        for (int off = 1; off < 64; off <<= 1) {
            int up = __shfl_up(wsum, off, 64);
            if (lane >= off) wsum += up;
        }
        if (lane == 63) swsum[wv] = wsum;
        __syncthreads();
        int wprefix = 0;
        for (int w = 0; w < wv; ++w) wprefix += swsum[w];
        const int chunk_prefix = wprefix + wsum - run;
#pragma unroll
        for (int e = 0; e < MAX_EPC; ++e)
            if (e < epc && base + e < L) sc[base + e] = chunk_prefix + local[e];
        __syncthreads();

        const int total = sc[L - 1];

        // ---- searchsorted(side='right') for this segment's frames ----
        if (tid < seg) {
            const int t = tt0 + tid;
            int p = -1;
            if (t < total) {
                int lo = 0, hi = L - 1;
                while (lo < hi) {
                    const int mid = (lo + hi) >> 1;
                    if (sc[mid] > t) hi = mid;
                    else             lo = mid + 1;
                }
                p = lo;
            }
            sidx[tid] = p;
        }
        __syncthreads();

        int nvalid = total - tt0;
        if (nvalid < 0) nvalid = 0;
        if (nvalid > seg) nvalid = seg;

        if (vecs == 64) {
            // ---- chunked LDS-staged copy (D == 256) ----
            int f = 0;
            while (f < nvalid) {
                const int w0 = sidx[f];                   // chunk's first row
                if (tid == 0) sf2 = nvalid;
                __syncthreads();                          // sf2 init; srows free
                if (tid > f && tid < nvalid && sidx[tid] >= w0 + ROWS)
                    atomicMin(&sf2, tid);
                // Phase A: stage rows w0 .. w0+ROWS-1 (clamped), coalesced
                int nr = L - w0; if (nr > ROWS) nr = ROWS;
                const float4* __restrict__ fbp =
                    (const float4*)feat + ((size_t)b * L + w0) * 64;
                for (int i = tid; i < nr * 64; i += 256)
                    srows[i] = fbp[i];
                __syncthreads();                          // rows + sf2 ready
                const int f2 = sf2;
                // Phase B: stream stores from LDS (no vmcnt load deps)
                float4* __restrict__ ob =
                    (float4*)out + (size_t)fb_ * 64 + lane;
                for (int j = f + wv; j < f2; j += 4) {
                    const int r = sidx[j] - w0;           // LDS broadcast
                    const float4 v = srows[r * 64 + lane];
                    ob[(size_t)j * 64] = v;               // 1 KiB wave store
                }
                f = f2;
            }
            // zero tail (invalid frames)
            const float4 z = make_float4(0.f, 0.f, 0.f, 0.f);
            float4* __restrict__ ob = (float4*)out + (size_t)fb_ * 64 + lane;
            for (int j = nvalid + wv; j < seg; j += 4)
                ob[(size_t)j * 64] = z;
        } else {
            // ---- generic fallback ----
            const float4* __restrict__ fbp =
                (const float4*)feat + (size_t)b * L * vecs;
            const float4 z = make_float4(0.f, 0.f, 0.f, 0.f);
            for (int fj = wv; fj < seg; fj += 4) {
                const int p = sidx[fj];
                float4* __restrict__ orow = (float4*)out + ((size_t)fb_ + fj) * vecs;
                if (p >= 0) {
                    const float4* __restrict__ irow = fbp + (size_t)p * vecs;
                    for (int i = lane; i < vecs; i += 64) orow[i] = irow[i];
                } else {
                    for (int i = lane; i < vecs; i += 64) orow[i] = z;
                }
            }
        }

        fb_ += seg;
        remaining -= seg;
    }
}

extern "C" void kernel_launch(void* const* d_in, const int* in_sizes, int n_in,
                              void* d_out, int out_size, void* d_ws, size_t ws_size,
                              hipStream_t stream) {
    const float* feat = (const float*)d_in[0];   // [B, L, D] fp32
    const int*   dur  = (const int*)d_in[1];     // [B, L] int32
    const int*   tlen = (const int*)d_in[2];     // scalar target_length (device)

    const int BL = in_sizes[1];                  // B*L
    const int D  = in_sizes[0] / in_sizes[1];    // feature dim
    const int BT = out_size / D;                 // B*T total frames

    const int grid = (BT + FPB - 1) / FPB;       // 1024 blocks for 16x8192
    lr_fused_kernel<<<grid, 256, 0, stream>>>(feat, dur, tlen, (float*)d_out,
                                              BL, BT, D);
}

// Round 8
// 145.882 us; speedup vs baseline: 1.0867x; 1.0867x over previous
//
#include <hip/hip_runtime.h>

#define MAX_L 2048   // max phonemes per batch for LDS cumsum
#define MAX_EPC 8    // max cum elements per thread (L <= 256*8)
#define FPB 128      // frames per block

// Fused length-regulator, depth-8 software-pipelined gather-copy.
// One 256-thread block per 128 output frames:
//   1) block computes its batch's duration cumsum in LDS (shuffle scan)
//   2) 128 threads binary-search in LDS -> sidx[128]
//   3) each wave copies 32 contiguous frames in 4 groups of 8:
//      group g+1's loads (unconditional, scalar row addr via readlane)
//      issue BEFORE group g's stores, so each store's data is >=16 VM ops
//      old -> s_waitcnt vmcnt(N>0), the store queue never drains.
__global__ __launch_bounds__(256) void lr_fused_kernel(
        const float* __restrict__ feat,
        const int* __restrict__ dur,
        const int* __restrict__ tlen,
        float* __restrict__ out,
        int BL, int BT, int D) {
    const int T = *tlen;
    const int B = BT / T;
    const int L = BL / B;
    const int vecs = D >> 2;

    __shared__ int sc[MAX_L];
    __shared__ int swsum[4];
    __shared__ int sidx[FPB];

    const long frame_base0 = (long)blockIdx.x * FPB;
    if (frame_base0 >= BT) return;

    const int tid  = threadIdx.x;
    const int lane = tid & 63;
    const int wv   = tid >> 6;

    long fb_ = frame_base0;
    long rem_l = (long)BT - frame_base0;
    int remaining = (int)(rem_l < FPB ? rem_l : (long)FPB);

    // Segment loop (block-uniform): one iteration when T % FPB == 0.
    while (remaining > 0) {
        const int b   = (int)(fb_ / T);
        const int tt0 = (int)(fb_ - (long)b * T);
        const int seg = remaining < (T - tt0) ? remaining : (T - tt0);

        // ---- cumsum of batch b's duration row into sc ----
        __syncthreads();  // protect sc/sidx reuse across segments
        const int epc  = (L + blockDim.x - 1) / blockDim.x;
        const int base = tid * epc;
        const int* __restrict__ drow = dur + (size_t)b * L;
        int local[MAX_EPC];
        int run = 0;
#pragma unroll
        for (int e = 0; e < MAX_EPC; ++e) {
            int v = 0;
            if (e < epc && base + e < L) v = drow[base + e];
            run += v;
            local[e] = run;
        }
        int wsum = run;
#pragma unroll
        for (int off = 1; off < 64; off <<= 1) {
            int up = __shfl_up(wsum, off, 64);
            if (lane >= off) wsum += up;
        }
        if (lane == 63) swsum[wv] = wsum;
        __syncthreads();
        int wprefix = 0;
        for (int w = 0; w < wv; ++w) wprefix += swsum[w];
        const int chunk_prefix = wprefix + wsum - run;
#pragma unroll
        for (int e = 0; e < MAX_EPC; ++e)
            if (e < epc && base + e < L) sc[base + e] = chunk_prefix + local[e];
        __syncthreads();

        const int total = sc[L - 1];

        // ---- searchsorted(side='right') for this segment's frames ----
        if (tid < seg) {
            const int t = tt0 + tid;
            int p = -1;
            if (t < total) {
                int lo = 0, hi = L - 1;
                while (lo < hi) {
                    const int mid = (lo + hi) >> 1;
                    if (sc[mid] > t) hi = mid;
                    else             lo = mid + 1;
                }
                p = lo;
            }
            sidx[tid] = p;
        }
        __syncthreads();

        int nvalid = total - tt0;
        if (nvalid < 0) nvalid = 0;
        if (nvalid > seg) nvalid = seg;

        // ---- copy ----
        if (seg == FPB && vecs == 64) {
            // Fast path (D == 256): wave wv owns 32 contiguous frames.
            // Depth-8 rotating buffer; all loads unconditional (row clamped),
            // invalid-tail select via block-uniform nvalid prefix.
            const float4* __restrict__ fbp =
                (const float4*)feat + (size_t)b * L * 64;
            float4* __restrict__ op =
                (float4*)out + ((size_t)fb_ + (size_t)wv * 32) * 64 + lane;
            const int si = sidx[wv * 32 + (lane & 31)];  // lane j: sidx[wv*32+j]
            const int fbase = wv * 32;                    // segment-local frame 0
            const float4 z = make_float4(0.f, 0.f, 0.f, 0.f);

            float4 buf[8];
#pragma unroll
            for (int j = 0; j < 8; ++j) {
                const int p = __builtin_amdgcn_readlane(si, j);  // SGPR
                buf[j] = fbp[(size_t)max(p, 0) * 64 + lane];
            }
#pragma unroll
            for (int g = 0; g < 4; ++g) {
                float4 nbuf[8];
                if (g < 3) {
#pragma unroll
                    for (int j = 0; j < 8; ++j) {
                        const int p = __builtin_amdgcn_readlane(si, (g + 1) * 8 + j);
                        nbuf[j] = fbp[(size_t)max(p, 0) * 64 + lane];
                    }
                }
#pragma unroll
                for (int j = 0; j < 8; ++j) {
                    float4 v = buf[j];
                    if (fbase + g * 8 + j >= nvalid) v = z;   // uniform select
                    op[(size_t)(g * 8 + j) * 64] = v;         // 1 KiB wave store
                }
#pragma unroll
                for (int j = 0; j < 8; ++j) buf[j] = nbuf[j];
            }
        } else {
            // Generic fallback: wave-strided frames, lane-strided float4s.
            const float4* __restrict__ fbp =
                (const float4*)feat + (size_t)b * L * vecs;
            const float4 z = make_float4(0.f, 0.f, 0.f, 0.f);
            for (int f = wv; f < seg; f += 4) {
                const int p = sidx[f];
                float4* __restrict__ orow = (float4*)out + ((size_t)fb_ + f) * vecs;
                if (p >= 0) {
                    const float4* __restrict__ irow = fbp + (size_t)p * vecs;
                    for (int i = lane; i < vecs; i += 64) orow[i] = irow[i];
                } else {
                    for (int i = lane; i < vecs; i += 64) orow[i] = z;
                }
            }
        }

        fb_ += seg;
        remaining -= seg;
    }
}

extern "C" void kernel_launch(void* const* d_in, const int* in_sizes, int n_in,
                              void* d_out, int out_size, void* d_ws, size_t ws_size,
                              hipStream_t stream) {
    const float* feat = (const float*)d_in[0];   // [B, L, D] fp32
    const int*   dur  = (const int*)d_in[1];     // [B, L] int32
    const int*   tlen = (const int*)d_in[2];     // scalar target_length (device)

    const int BL = in_sizes[1];                  // B*L
    const int D  = in_sizes[0] / in_sizes[1];    // feature dim
    const int BT = out_size / D;                 // B*T total frames

    const int grid = (BT + FPB - 1) / FPB;       // 1024 blocks for 16x8192
    lr_fused_kernel<<<grid, 256, 0, stream>>>(feat, dur, tlen, (float*)d_out,
                                              BL, BT, D);
}